// Round 7
// baseline (298.297 us; speedup 1.0000x reference)
//
#include <hip/hip_runtime.h>

#define NN 19        // nodes
#define NT 4096
#define LAT 512
#define HID 2048
#define NE 342       // edges

// ---------------------------------------------------------------------------
// Build M = I + adjacency-count (19x19) into sM from edge_idx. cnt[] aliases
// scratch LDS. Edge buffer may be int64 (pairs of int32) or int32, detected
// via odd-word check (values in [0,19) => int64 high words all zero).
// ---------------------------------------------------------------------------
__device__ __forceinline__ void build_M(const int* __restrict__ ei, float* sM,
                                        int* scratch, int t, int bs) {
    int* cnt = scratch;
    int* flag = scratch + NN * NN;
    if (t == 0) *flag = 0;
    for (int i = t; i < NN * NN; i += bs) cnt[i] = 0;
    __syncthreads();
    int f = 0;
    for (int i = t; i < NE; i += bs) f |= ei[2 * i + 1];
    if (f) atomicOr(flag, 1);
    __syncthreads();
    const bool i64 = (*flag == 0);
    for (int i = t; i < NE; i += bs) {
        const int s = i64 ? ei[2 * i] : ei[i];
        const int d = i64 ? ei[2 * NE + 2 * i] : ei[NE + i];
        atomicAdd(&cnt[d * NN + s], 1);
    }
    __syncthreads();
    for (int i = t; i < NN * NN; i += bs)
        sM[i] = (float)cnt[i] + ((i / NN) == (i % NN) ? 1.f : 0.f);
    __syncthreads();
}

// ---------------------------------------------------------------------------
// GEMM inner: acc[19][4 cols] over a BK k-slice staged in sA[k*21+i].
// float4 weight loads, 8 in flight (128 B/lane). Writes partial chunk kc.
// ---------------------------------------------------------------------------
template <int BK, int N>
__device__ __forceinline__ void gemm_inner(int col, int kc,
                                           const float* __restrict__ W,
                                           float* __restrict__ part,
                                           const float* __restrict__ sA) {
    const int k0 = kc * BK;
    const float4* __restrict__ w = (const float4*)(W + (size_t)k0 * N + col);
    float4 acc[NN];
#pragma unroll
    for (int i = 0; i < NN; ++i) acc[i] = make_float4(0.f, 0.f, 0.f, 0.f);
#pragma unroll 1
    for (int kk = 0; kk < BK; kk += 8) {
        float4 wb[8];
#pragma unroll
        for (int u = 0; u < 8; ++u) wb[u] = w[(size_t)(kk + u) * (N / 4)];
#pragma unroll
        for (int u = 0; u < 8; ++u) {
#pragma unroll
            for (int i = 0; i < NN; ++i) {
                const float av = sA[(kk + u) * 21 + i];
                acc[i].x = fmaf(av, wb[u].x, acc[i].x);
                acc[i].y = fmaf(av, wb[u].y, acc[i].y);
                acc[i].z = fmaf(av, wb[u].z, acc[i].z);
                acc[i].w = fmaf(av, wb[u].w, acc[i].w);
            }
        }
    }
    float* __restrict__ p = part + (size_t)kc * NN * N + col;
#pragma unroll
    for (int i = 0; i < NN; ++i) *(float4*)(p + (size_t)i * N) = acc[i];
}

// K1: part1 = (M @ z) @ W1a.  K=512, BK=32; grid (cb=2, kc=16). Zeroes ticket.
__global__ __launch_bounds__(256, 2) void gemm_l1a(const float* __restrict__ z,
                                                   const int* __restrict__ ei,
                                                   const float* __restrict__ W1a,
                                                   float* __restrict__ part1,
                                                   unsigned int* __restrict__ counter) {
    __shared__ __align__(16) float sA[32 * 21];
    __shared__ __align__(16) float sZ[32 * 21];
    __shared__ float sM[NN * NN];
    __shared__ int scratch[NN * NN + 1];
    const int t = threadIdx.x, cb = blockIdx.x, kc = blockIdx.y;
    const int k0 = kc * 32;
    if (cb == 0 && kc == 0 && t == 0) *counter = 0u;
    build_M(ei, sM, scratch, t, 256);
    for (int idx = t; idx < NN * 32; idx += 256) {
        const int s = idx / 32, c = idx % 32;
        sZ[c * 21 + s] = z[(size_t)s * LAT + k0 + c];
    }
    __syncthreads();
    for (int idx = t; idx < NN * 32; idx += 256) {
        const int i = idx / 32, c = idx % 32;
        float acc = 0.f;
#pragma unroll
        for (int s = 0; s < NN; ++s) acc = fmaf(sM[i * NN + s], sZ[c * 21 + s], acc);
        sA[c * 21 + i] = acc;
    }
    __syncthreads();
    gemm_inner<32, HID>(cb * 1024 + 4 * t, kc, W1a, part1, sA);
}

// K2: part2 = relu(reduce16(part1)+b1a) @ W1b.  K=2048, BK=64; grid (2, 32)
__global__ __launch_bounds__(256, 2) void gemm_l1b(const float* __restrict__ part1,
                                                   const float* __restrict__ b1a,
                                                   const float* __restrict__ W1b,
                                                   float* __restrict__ part2) {
    __shared__ __align__(16) float sA[64 * 21];
    const int t = threadIdx.x, cb = blockIdx.x, kc = blockIdx.y;
    const int k0 = kc * 64;
    for (int idx = t; idx < NN * 64; idx += 256) {
        const int i = idx / 64, c = idx % 64;
        const int k = k0 + c;
        float s = b1a[k];
#pragma unroll
        for (int cc = 0; cc < 16; ++cc) s += part1[((size_t)cc * NN + i) * HID + k];
        sA[c * 21 + i] = s > 0.f ? s : 0.f;
    }
    __syncthreads();
    gemm_inner<64, HID>(cb * 1024 + 4 * t, kc, W1b, part2, sA);
}

// K3: part3 = (M @ relu(reduce32(part2)+b1b)) @ W2a.  K=2048, BK=64; grid (4,32)
__global__ __launch_bounds__(256, 2) void gemm_l2a(const float* __restrict__ part2,
                                                   const float* __restrict__ b1b,
                                                   const int* __restrict__ ei,
                                                   const float* __restrict__ W2a,
                                                   float* __restrict__ part3) {
    __shared__ __align__(16) float sA[64 * 21];
    __shared__ __align__(16) float sZ[64 * 21];
    __shared__ float sM[NN * NN];
    __shared__ int scratch[NN * NN + 1];
    const int t = threadIdx.x, cb = blockIdx.x, kc = blockIdx.y;
    const int k0 = kc * 64;
    build_M(ei, sM, scratch, t, 256);
    for (int idx = t; idx < NN * 64; idx += 256) {
        const int i = idx / 64, c = idx % 64;
        const int k = k0 + c;
        float s = b1b[k];
#pragma unroll
        for (int cc = 0; cc < 32; ++cc) s += part2[((size_t)cc * NN + i) * HID + k];
        sZ[c * 21 + i] = s > 0.f ? s : 0.f;
    }
    __syncthreads();
    for (int idx = t; idx < NN * 64; idx += 256) {
        const int i = idx / 64, c = idx % 64;
        float acc = 0.f;
#pragma unroll
        for (int s = 0; s < NN; ++s) acc = fmaf(sM[i * NN + s], sZ[c * 21 + s], acc);
        sA[c * 21 + i] = acc;
    }
    __syncthreads();
    gemm_inner<64, NT>(cb * 1024 + 4 * t, kc, W2a, part3, sA);
}

// K4: part4 = relu(reduce32(part3)+b2a) @ W2b.  K=4096, BK=64; grid (4, 64)
__global__ __launch_bounds__(256, 2) void gemm_l2b(const float* __restrict__ part3,
                                                   const float* __restrict__ b2a,
                                                   const float* __restrict__ W2b,
                                                   float* __restrict__ part4) {
    __shared__ __align__(16) float sA[64 * 21];
    const int t = threadIdx.x, cb = blockIdx.x, kc = blockIdx.y;
    const int k0 = kc * 64;
    for (int idx = t; idx < NN * 64; idx += 256) {
        const int i = idx / 64, c = idx % 64;
        const int k = k0 + c;
        float s = b2a[k];
#pragma unroll
        for (int cc = 0; cc < 32; ++cc) s += part3[((size_t)cc * NN + i) * NT + k];
        sA[c * 21 + i] = s > 0.f ? s : 0.f;
    }
    __syncthreads();
    gemm_inner<64, NT>(cb * 1024 + 4 * t, kc, W2b, part4, sA);
}

// ---------------------------------------------------------------------------
// K5 (fused classifier): 1024 blocks x 256 threads, BK=76 rows each.
//   phase 1: sF[0..76) = reduce64(part4)+b2b  -> out+1 and LDS
//   phase 2: block partial c[512] = sF @ Wc1[k0:k0+76); thread owns 2 cols,
//            19-deep float2 load batches (152 B/lane in flight).
//   phase 3: scalar = c . Wc2  (LDS tree), scal[bid] = scalar
//   ticket: last block sums 1024 scalars + bc1.Wc2 + bc2 -> sigmoid -> out[0]
// ---------------------------------------------------------------------------
__global__ __launch_bounds__(256, 4) void cls_fused(const float* __restrict__ part4,
                                                    const float* __restrict__ b2b,
                                                    const float* __restrict__ Wc1,
                                                    const float* __restrict__ bc1,
                                                    const float* __restrict__ Wc2,
                                                    const float* __restrict__ bc2,
                                                    float* __restrict__ out,
                                                    float* __restrict__ scal,
                                                    unsigned int* __restrict__ counter) {
    __shared__ float sF[76];
    __shared__ float red[256];
    __shared__ int lastFlag;
    const int t = threadIdx.x;
    const int bid = blockIdx.x;
    const int k0 = bid * 76;

    // phase 1: e = t&127 (<76 active), h = t>>7 handles 32 chunks
    const int e = t & 127, h = t >> 7;
    float partial = 0.f;
    if (e < 76) {
        const int fidx = k0 + e;
        const int i = fidx >> 12, n = fidx & 4095;
        const float* __restrict__ p = part4 + ((size_t)(h * 32 * NN + i)) * NT + n;
#pragma unroll 16
        for (int cc = 0; cc < 32; ++cc) partial += p[(size_t)cc * NN * NT];
    }
    if (e < 76 && h) red[e] = partial;
    __syncthreads();
    if (e < 76 && !h) {
        const int fidx = k0 + e;
        const float s = partial + red[e] + b2b[fidx & 4095];
        sF[e] = s;
        out[1 + fidx] = s;
    }
    __syncthreads();

    // phase 2: thread owns cols {2t, 2t+1}
    const float2* __restrict__ w2 = (const float2*)Wc1 + (size_t)k0 * 256 + t;
    float accx = 0.f, accy = 0.f;
#pragma unroll 1
    for (int g = 0; g < 4; ++g) {
        float2 wb[19];
        float fv[19];
#pragma unroll
        for (int u = 0; u < 19; ++u) wb[u] = w2[(size_t)(g * 19 + u) * 256];
#pragma unroll
        for (int u = 0; u < 19; ++u) fv[u] = sF[g * 19 + u];
#pragma unroll
        for (int u = 0; u < 19; ++u) {
            accx = fmaf(fv[u], wb[u].x, accx);
            accy = fmaf(fv[u], wb[u].y, accy);
        }
    }

    // phase 3: dot with Wc2, tree-reduce to block scalar
    const float2 wv = ((const float2*)Wc2)[t];
    red[t] = accx * wv.x + accy * wv.y;
    __syncthreads();
    for (int off = 128; off > 0; off >>= 1) {
        if (t < off) red[t] += red[t + off];
        __syncthreads();
    }
    if (t == 0) scal[bid] = red[0];
    __threadfence();  // release scal write device-wide (cross-XCD)
    __syncthreads();
    if (t == 0) lastFlag = (atomicAdd(counter, 1u) == 1023u) ? 1 : 0;
    __syncthreads();
    if (!lastFlag) return;
    __threadfence();  // acquire before reading all scal

    float s = 0.f;
#pragma unroll
    for (int c = 0; c < 4; ++c) s += scal[t + 256 * c];
    const float2 b1 = ((const float2*)bc1)[t];
    s += b1.x * wv.x + b1.y * wv.y;
    red[t] = s;
    __syncthreads();
    for (int off = 128; off > 0; off >>= 1) {
        if (t < off) red[t] += red[t + off];
        __syncthreads();
    }
    if (t == 0) out[0] = 1.f / (1.f + expf(-(red[0] + bc2[0])));
}

extern "C" void kernel_launch(void* const* d_in, const int* in_sizes, int n_in,
                              void* d_out, int out_size, void* d_ws, size_t ws_size,
                              hipStream_t stream) {
    const float* z   = (const float*)d_in[0];
    const int*   ei  = (const int*)d_in[1];
    const float* W1a = (const float*)d_in[2];
    const float* b1a = (const float*)d_in[3];
    const float* W1b = (const float*)d_in[4];
    const float* b1b = (const float*)d_in[5];
    const float* W2a = (const float*)d_in[6];
    const float* b2a = (const float*)d_in[7];
    const float* W2b = (const float*)d_in[8];
    const float* b2b = (const float*)d_in[9];
    const float* Wc1 = (const float*)d_in[10];
    const float* bc1 = (const float*)d_in[11];
    const float* Wc2 = (const float*)d_in[12];
    const float* bc2 = (const float*)d_in[13];
    float* out = (float*)d_out;
    float* ws  = (float*)d_ws;

    // workspace layout (float offsets)
    unsigned int* counter = (unsigned int*)ws;  // ticket, reset by K1 each call
    float* part1 = ws + 262144;    // 16*19*2048 =   622,592
    float* part2 = ws + 1048576;   // 32*19*2048 = 1,245,184
    float* part3 = ws + 2359296;   // 32*19*4096 = 2,490,368
    float* part4 = ws + 4980736;   // 64*19*4096 = 4,980,736
    float* scal  = ws + 10485760;  // 1024

    gemm_l1a<<<dim3(2, 16), 256, 0, stream>>>(z, ei, W1a, part1, counter);
    gemm_l1b<<<dim3(2, 32), 256, 0, stream>>>(part1, b1a, W1b, part2);
    gemm_l2a<<<dim3(4, 32), 256, 0, stream>>>(part2, b1b, ei, W2a, part3);
    gemm_l2b<<<dim3(4, 64), 256, 0, stream>>>(part3, b2a, W2b, part4);
    cls_fused<<<1024, 256, 0, stream>>>(part4, b2b, Wc1, bc1, Wc2, bc2,
                                        out, scal, counter);
}

// Round 8
// 221.540 us; speedup vs baseline: 1.3465x; 1.3465x over previous
//
#include <hip/hip_runtime.h>

#define NN 19        // nodes
#define NT 4096
#define LAT 512
#define HID 2048
#define NE 342       // edges

// ---------------------------------------------------------------------------
// Async global->LDS DMA, 16 B per lane per call (global_load_lds_dwordx4).
// gsrc is PER-LANE (base + lane*16B); ldst must be WAVE-UNIFORM; HW writes
// lane i's 16 B at ldst + i*16.  (CK-style addrspace casts.)
// ---------------------------------------------------------------------------
__device__ __forceinline__ void stage16B(const void* gsrc, void* ldst) {
    __builtin_amdgcn_global_load_lds(
        reinterpret_cast<const __attribute__((address_space(1))) void*>(
            reinterpret_cast<uintptr_t>(gsrc)),
        reinterpret_cast<__attribute__((address_space(3))) void*>(
            reinterpret_cast<uintptr_t>(ldst)),
        16, 0, 0);
}

// ---------------------------------------------------------------------------
// Build M = I + adjacency-count (19x19) into sM from edge_idx. cnt[] aliases
// scratch LDS. Edge buffer may be int64 (pairs of int32) or int32, detected
// via odd-word check (values in [0,19) => int64 high words all zero).
// ---------------------------------------------------------------------------
__device__ __forceinline__ void build_M(const int* __restrict__ ei, float* sM,
                                        int* scratch, int t, int bs) {
    int* cnt = scratch;
    int* flag = scratch + NN * NN;
    if (t == 0) *flag = 0;
    for (int i = t; i < NN * NN; i += bs) cnt[i] = 0;
    __syncthreads();
    int f = 0;
    for (int i = t; i < NE; i += bs) f |= ei[2 * i + 1];
    if (f) atomicOr(flag, 1);
    __syncthreads();
    const bool i64 = (*flag == 0);
    for (int i = t; i < NE; i += bs) {
        const int s = i64 ? ei[2 * i] : ei[i];
        const int d = i64 ? ei[2 * NE + 2 * i] : ei[NE + i];
        atomicAdd(&cnt[d * NN + s], 1);
    }
    __syncthreads();
    for (int i = t; i < NN * NN; i += bs)
        sM[i] = (float)cnt[i] + ((i / NN) == (i % NN) ? 1.f : 0.f);
    __syncthreads();
}

// ---------------------------------------------------------------------------
// GEMM inner: acc[19][4 cols] over a BK k-slice staged in sA[k*21+i].
// ---------------------------------------------------------------------------
template <int BK, int N>
__device__ __forceinline__ void gemm_inner(int col, int kc,
                                           const float* __restrict__ W,
                                           float* __restrict__ part,
                                           const float* __restrict__ sA) {
    const int k0 = kc * BK;
    const float4* __restrict__ w = (const float4*)(W + (size_t)k0 * N + col);
    float4 acc[NN];
#pragma unroll
    for (int i = 0; i < NN; ++i) acc[i] = make_float4(0.f, 0.f, 0.f, 0.f);
#pragma unroll 1
    for (int kk = 0; kk < BK; kk += 8) {
        float4 wb[8];
#pragma unroll
        for (int u = 0; u < 8; ++u) wb[u] = w[(size_t)(kk + u) * (N / 4)];
#pragma unroll
        for (int u = 0; u < 8; ++u) {
#pragma unroll
            for (int i = 0; i < NN; ++i) {
                const float av = sA[(kk + u) * 21 + i];
                acc[i].x = fmaf(av, wb[u].x, acc[i].x);
                acc[i].y = fmaf(av, wb[u].y, acc[i].y);
                acc[i].z = fmaf(av, wb[u].z, acc[i].z);
                acc[i].w = fmaf(av, wb[u].w, acc[i].w);
            }
        }
    }
    float* __restrict__ p = part + (size_t)kc * NN * N + col;
#pragma unroll
    for (int i = 0; i < NN; ++i) *(float4*)(p + (size_t)i * N) = acc[i];
}

// K1: part1 = (M @ z) @ W1a.  K=512, BK=32; grid (cb=2, kc=16). Zeroes ticket.
__global__ __launch_bounds__(256, 2) void gemm_l1a(const float* __restrict__ z,
                                                   const int* __restrict__ ei,
                                                   const float* __restrict__ W1a,
                                                   float* __restrict__ part1,
                                                   unsigned int* __restrict__ counter) {
    __shared__ __align__(16) float sA[32 * 21];
    __shared__ __align__(16) float sZ[32 * 21];
    __shared__ float sM[NN * NN];
    __shared__ int scratch[NN * NN + 1];
    const int t = threadIdx.x, cb = blockIdx.x, kc = blockIdx.y;
    const int k0 = kc * 32;
    if (cb == 0 && kc == 0 && t == 0) *counter = 0u;
    build_M(ei, sM, scratch, t, 256);
    for (int idx = t; idx < NN * 32; idx += 256) {
        const int s = idx / 32, c = idx % 32;
        sZ[c * 21 + s] = z[(size_t)s * LAT + k0 + c];
    }
    __syncthreads();
    for (int idx = t; idx < NN * 32; idx += 256) {
        const int i = idx / 32, c = idx % 32;
        float acc = 0.f;
#pragma unroll
        for (int s = 0; s < NN; ++s) acc = fmaf(sM[i * NN + s], sZ[c * 21 + s], acc);
        sA[c * 21 + i] = acc;
    }
    __syncthreads();
    gemm_inner<32, HID>(cb * 1024 + 4 * t, kc, W1a, part1, sA);
}

// K2: part2 = relu(reduce16(part1)+b1a) @ W1b.  K=2048, BK=64; grid (2, 32)
__global__ __launch_bounds__(256, 2) void gemm_l1b(const float* __restrict__ part1,
                                                   const float* __restrict__ b1a,
                                                   const float* __restrict__ W1b,
                                                   float* __restrict__ part2) {
    __shared__ __align__(16) float sA[64 * 21];
    const int t = threadIdx.x, cb = blockIdx.x, kc = blockIdx.y;
    const int k0 = kc * 64;
    for (int idx = t; idx < NN * 64; idx += 256) {
        const int i = idx / 64, c = idx % 64;
        const int k = k0 + c;
        float s = b1a[k];
#pragma unroll
        for (int cc = 0; cc < 16; ++cc) s += part1[((size_t)cc * NN + i) * HID + k];
        sA[c * 21 + i] = s > 0.f ? s : 0.f;
    }
    __syncthreads();
    gemm_inner<64, HID>(cb * 1024 + 4 * t, kc, W1b, part2, sA);
}

// K3: part3 = (M @ relu(reduce32(part2)+b1b)) @ W2a.  K=2048, BK=64; grid (4,32)
__global__ __launch_bounds__(256, 2) void gemm_l2a(const float* __restrict__ part2,
                                                   const float* __restrict__ b1b,
                                                   const int* __restrict__ ei,
                                                   const float* __restrict__ W2a,
                                                   float* __restrict__ part3) {
    __shared__ __align__(16) float sA[64 * 21];
    __shared__ __align__(16) float sZ[64 * 21];
    __shared__ float sM[NN * NN];
    __shared__ int scratch[NN * NN + 1];
    const int t = threadIdx.x, cb = blockIdx.x, kc = blockIdx.y;
    const int k0 = kc * 64;
    build_M(ei, sM, scratch, t, 256);
    for (int idx = t; idx < NN * 64; idx += 256) {
        const int i = idx / 64, c = idx % 64;
        const int k = k0 + c;
        float s = b1b[k];
#pragma unroll
        for (int cc = 0; cc < 32; ++cc) s += part2[((size_t)cc * NN + i) * HID + k];
        sZ[c * 21 + i] = s > 0.f ? s : 0.f;
    }
    __syncthreads();
    for (int idx = t; idx < NN * 64; idx += 256) {
        const int i = idx / 64, c = idx % 64;
        float acc = 0.f;
#pragma unroll
        for (int s = 0; s < NN; ++s) acc = fmaf(sM[i * NN + s], sZ[c * 21 + s], acc);
        sA[c * 21 + i] = acc;
    }
    __syncthreads();
    gemm_inner<64, NT>(cb * 1024 + 4 * t, kc, W2a, part3, sA);
}

// K4: part4 = relu(reduce32(part3)+b2a) @ W2b.  K=4096, BK=64; grid (4, 64)
__global__ __launch_bounds__(256, 2) void gemm_l2b(const float* __restrict__ part3,
                                                   const float* __restrict__ b2a,
                                                   const float* __restrict__ W2b,
                                                   float* __restrict__ part4) {
    __shared__ __align__(16) float sA[64 * 21];
    const int t = threadIdx.x, cb = blockIdx.x, kc = blockIdx.y;
    const int k0 = kc * 64;
    for (int idx = t; idx < NN * 64; idx += 256) {
        const int i = idx / 64, c = idx % 64;
        const int k = k0 + c;
        float s = b2a[k];
#pragma unroll
        for (int cc = 0; cc < 32; ++cc) s += part3[((size_t)cc * NN + i) * NT + k];
        sA[c * 21 + i] = s > 0.f ? s : 0.f;
    }
    __syncthreads();
    gemm_inner<64, NT>(cb * 1024 + 4 * t, kc, W2b, part4, sA);
}

// ---------------------------------------------------------------------------
// K5 (fused classifier, DMA-staged): 1024 blocks x 256 threads, 76 rows each.
//   phase 1: sF[0..76) = reduce64(part4)+b2b  -> out+1 and LDS
//   phase 2: 19 chunks of 4 rows; Wc1 slice DMA'd to LDS via global_load_lds
//            (4-buffer pipeline, counted vmcnt, 1 barrier/chunk);
//            thread owns 2 cols, accumulates sF[row]*Wc1[row][col].
//   phase 3: dot with Wc2, tree-reduce, scal[bid]; ticket: last block sums.
// ---------------------------------------------------------------------------
__global__ __launch_bounds__(256, 4) void cls_fused(const float* __restrict__ part4,
                                                    const float* __restrict__ b2b,
                                                    const float* __restrict__ Wc1,
                                                    const float* __restrict__ bc1,
                                                    const float* __restrict__ Wc2,
                                                    const float* __restrict__ bc2,
                                                    float* __restrict__ out,
                                                    float* __restrict__ scal,
                                                    unsigned int* __restrict__ counter) {
    __shared__ __align__(16) float sW[4 * 2048];  // 4 bufs x (4 rows x 512)
    __shared__ float sF[76];
    __shared__ float red[256];
    __shared__ int lastFlag;
    const int t = threadIdx.x;
    const int lane = t & 63, wid = t >> 6;
    const int bid = blockIdx.x;
    const int k0 = bid * 76;

    // ---- issue first two DMA chunks before phase 1 (overlap) ----
    const float* __restrict__ wbase = Wc1 + (size_t)k0 * 512;
    {
        const float* g0 = wbase + wid * 512 + lane * 4;
        float* l0 = sW + wid * 512;
        stage16B(g0, l0);
        stage16B(g0 + 256, l0 + 256);
        const float* g1 = wbase + 2048 + wid * 512 + lane * 4;
        float* l1 = sW + 2048 + wid * 512;
        stage16B(g1, l1);
        stage16B(g1 + 256, l1 + 256);
    }

    // ---- phase 1: flat segment = reduce64(part4)+b2b ----
    const int e = t & 127, h = t >> 7;
    float partial = 0.f;
    if (e < 76) {
        const int fidx = k0 + e;
        const int i = fidx >> 12, n = fidx & 4095;
        const float* __restrict__ p = part4 + ((size_t)(h * 32 * NN + i)) * NT + n;
#pragma unroll 16
        for (int cc = 0; cc < 32; ++cc) partial += p[(size_t)cc * NN * NT];
    }
    if (e < 76 && h) red[e] = partial;
    __syncthreads();
    if (e < 76 && !h) {
        const int fidx = k0 + e;
        const float s = partial + red[e] + b2b[fidx & 4095];
        sF[e] = s;
        out[1 + fidx] = s;
    }

    // ---- phase 2: 19 chunks, 4-buffer DMA pipeline ----
    float accx = 0.f, accy = 0.f;
#pragma unroll 1
    for (int c = 0; c < 19; ++c) {
        if (c + 2 < 19) {
            const float* g = wbase + (size_t)(c + 2) * 2048 + wid * 512 + lane * 4;
            float* l = sW + ((c + 2) & 3) * 2048 + wid * 512;
            stage16B(g, l);
            stage16B(g + 256, l + 256);
            asm volatile("s_waitcnt vmcnt(4)" ::: "memory");
        } else if (c + 1 < 19) {
            asm volatile("s_waitcnt vmcnt(2)" ::: "memory");
        } else {
            asm volatile("s_waitcnt vmcnt(0)" ::: "memory");
        }
        __syncthreads();
        const float* wb = sW + (c & 3) * 2048;
#pragma unroll
        for (int r = 0; r < 4; ++r) {
            const float2 wv = *(const float2*)(wb + r * 512 + 2 * t);
            const float f = sF[c * 4 + r];
            accx = fmaf(f, wv.x, accx);
            accy = fmaf(f, wv.y, accy);
        }
    }

    // ---- phase 3: dot with Wc2, block scalar, ticket tail ----
    const float2 wv2 = ((const float2*)Wc2)[t];
    __syncthreads();
    red[t] = accx * wv2.x + accy * wv2.y;
    __syncthreads();
    for (int off = 128; off > 0; off >>= 1) {
        if (t < off) red[t] += red[t + off];
        __syncthreads();
    }
    if (t == 0) scal[bid] = red[0];
    __threadfence();
    __syncthreads();
    if (t == 0) lastFlag = (atomicAdd(counter, 1u) == 1023u) ? 1 : 0;
    __syncthreads();
    if (!lastFlag) return;
    __threadfence();

    float s = 0.f;
#pragma unroll
    for (int c = 0; c < 4; ++c) s += scal[t + 256 * c];
    const float2 b1 = ((const float2*)bc1)[t];
    s += b1.x * wv2.x + b1.y * wv2.y;
    red[t] = s;
    __syncthreads();
    for (int off = 128; off > 0; off >>= 1) {
        if (t < off) red[t] += red[t + off];
        __syncthreads();
    }
    if (t == 0) out[0] = 1.f / (1.f + expf(-(red[0] + bc2[0])));
}

extern "C" void kernel_launch(void* const* d_in, const int* in_sizes, int n_in,
                              void* d_out, int out_size, void* d_ws, size_t ws_size,
                              hipStream_t stream) {
    const float* z   = (const float*)d_in[0];
    const int*   ei  = (const int*)d_in[1];
    const float* W1a = (const float*)d_in[2];
    const float* b1a = (const float*)d_in[3];
    const float* W1b = (const float*)d_in[4];
    const float* b1b = (const float*)d_in[5];
    const float* W2a = (const float*)d_in[6];
    const float* b2a = (const float*)d_in[7];
    const float* W2b = (const float*)d_in[8];
    const float* b2b = (const float*)d_in[9];
    const float* Wc1 = (const float*)d_in[10];
    const float* bc1 = (const float*)d_in[11];
    const float* Wc2 = (const float*)d_in[12];
    const float* bc2 = (const float*)d_in[13];
    float* out = (float*)d_out;
    float* ws  = (float*)d_ws;

    // workspace layout (float offsets)
    unsigned int* counter = (unsigned int*)ws;  // ticket, reset by K1 each call
    float* part1 = ws + 262144;    // 16*19*2048 =   622,592
    float* part2 = ws + 1048576;   // 32*19*2048 = 1,245,184
    float* part3 = ws + 2359296;   // 32*19*4096 = 2,490,368
    float* part4 = ws + 4980736;   // 64*19*4096 = 4,980,736
    float* scal  = ws + 10485760;  // 1024

    gemm_l1a<<<dim3(2, 16), 256, 0, stream>>>(z, ei, W1a, part1, counter);
    gemm_l1b<<<dim3(2, 32), 256, 0, stream>>>(part1, b1a, W1b, part2);
    gemm_l2a<<<dim3(4, 32), 256, 0, stream>>>(part2, b1b, ei, W2a, part3);
    gemm_l2b<<<dim3(4, 64), 256, 0, stream>>>(part3, b2a, W2b, part4);
    cls_fused<<<1024, 256, 0, stream>>>(part4, b2b, Wc1, bc1, Wc2, bc2,
                                        out, scal, counter);
}

// Round 9
// 217.258 us; speedup vs baseline: 1.3730x; 1.0197x over previous
//
#include <hip/hip_runtime.h>

#define NN 19        // nodes
#define NT 4096
#define LAT 512
#define HID 2048
#define NE 342       // edges

// ---------------------------------------------------------------------------
// Async global->LDS DMA, 16 B per lane per call (global_load_lds_dwordx4).
// gsrc is PER-LANE (base + lane*16B); ldst must be WAVE-UNIFORM; HW writes
// lane i's 16 B at ldst + i*16.  (CK-style addrspace casts.)
// ---------------------------------------------------------------------------
__device__ __forceinline__ void stage16B(const void* gsrc, void* ldst) {
    __builtin_amdgcn_global_load_lds(
        reinterpret_cast<const __attribute__((address_space(1))) void*>(
            reinterpret_cast<uintptr_t>(gsrc)),
        reinterpret_cast<__attribute__((address_space(3))) void*>(
            reinterpret_cast<uintptr_t>(ldst)),
        16, 0, 0);
}

// ---------------------------------------------------------------------------
// Build M = I + adjacency-count (19x19) into sM from edge_idx. cnt[] aliases
// scratch LDS. Edge buffer may be int64 (pairs of int32) or int32, detected
// via odd-word check (values in [0,19) => int64 high words all zero).
// ---------------------------------------------------------------------------
__device__ __forceinline__ void build_M(const int* __restrict__ ei, float* sM,
                                        int* scratch, int t, int bs) {
    int* cnt = scratch;
    int* flag = scratch + NN * NN;
    if (t == 0) *flag = 0;
    for (int i = t; i < NN * NN; i += bs) cnt[i] = 0;
    __syncthreads();
    int f = 0;
    for (int i = t; i < NE; i += bs) f |= ei[2 * i + 1];
    if (f) atomicOr(flag, 1);
    __syncthreads();
    const bool i64 = (*flag == 0);
    for (int i = t; i < NE; i += bs) {
        const int s = i64 ? ei[2 * i] : ei[i];
        const int d = i64 ? ei[2 * NE + 2 * i] : ei[NE + i];
        atomicAdd(&cnt[d * NN + s], 1);
    }
    __syncthreads();
    for (int i = t; i < NN * NN; i += bs)
        sM[i] = (float)cnt[i] + ((i / NN) == (i % NN) ? 1.f : 0.f);
    __syncthreads();
}

// ---------------------------------------------------------------------------
// GEMM inner: acc[19][4 cols] over a BK k-slice staged in sA[k*21+i].
// ---------------------------------------------------------------------------
template <int BK, int N>
__device__ __forceinline__ void gemm_inner(int col, int kc,
                                           const float* __restrict__ W,
                                           float* __restrict__ part,
                                           const float* __restrict__ sA) {
    const int k0 = kc * BK;
    const float4* __restrict__ w = (const float4*)(W + (size_t)k0 * N + col);
    float4 acc[NN];
#pragma unroll
    for (int i = 0; i < NN; ++i) acc[i] = make_float4(0.f, 0.f, 0.f, 0.f);
#pragma unroll 1
    for (int kk = 0; kk < BK; kk += 8) {
        float4 wb[8];
#pragma unroll
        for (int u = 0; u < 8; ++u) wb[u] = w[(size_t)(kk + u) * (N / 4)];
#pragma unroll
        for (int u = 0; u < 8; ++u) {
#pragma unroll
            for (int i = 0; i < NN; ++i) {
                const float av = sA[(kk + u) * 21 + i];
                acc[i].x = fmaf(av, wb[u].x, acc[i].x);
                acc[i].y = fmaf(av, wb[u].y, acc[i].y);
                acc[i].z = fmaf(av, wb[u].z, acc[i].z);
                acc[i].w = fmaf(av, wb[u].w, acc[i].w);
            }
        }
    }
    float* __restrict__ p = part + (size_t)kc * NN * N + col;
#pragma unroll
    for (int i = 0; i < NN; ++i) *(float4*)(p + (size_t)i * N) = acc[i];
}

// K1: part1 = (M @ z) @ W1a.  K=512, BK=32; grid (cb=2, kc=16). Zeroes ticket.
__global__ __launch_bounds__(256, 2) void gemm_l1a(const float* __restrict__ z,
                                                   const int* __restrict__ ei,
                                                   const float* __restrict__ W1a,
                                                   float* __restrict__ part1,
                                                   unsigned int* __restrict__ counter) {
    __shared__ __align__(16) float sA[32 * 21];
    __shared__ __align__(16) float sZ[32 * 21];
    __shared__ float sM[NN * NN];
    __shared__ int scratch[NN * NN + 1];
    const int t = threadIdx.x, cb = blockIdx.x, kc = blockIdx.y;
    const int k0 = kc * 32;
    if (cb == 0 && kc == 0 && t == 0) *counter = 0u;
    build_M(ei, sM, scratch, t, 256);
    for (int idx = t; idx < NN * 32; idx += 256) {
        const int s = idx / 32, c = idx % 32;
        sZ[c * 21 + s] = z[(size_t)s * LAT + k0 + c];
    }
    __syncthreads();
    for (int idx = t; idx < NN * 32; idx += 256) {
        const int i = idx / 32, c = idx % 32;
        float acc = 0.f;
#pragma unroll
        for (int s = 0; s < NN; ++s) acc = fmaf(sM[i * NN + s], sZ[c * 21 + s], acc);
        sA[c * 21 + i] = acc;
    }
    __syncthreads();
    gemm_inner<32, HID>(cb * 1024 + 4 * t, kc, W1a, part1, sA);
}

// K2: part2 = relu(reduce16(part1)+b1a) @ W1b.  K=2048, BK=64; grid (2, 32)
__global__ __launch_bounds__(256, 2) void gemm_l1b(const float* __restrict__ part1,
                                                   const float* __restrict__ b1a,
                                                   const float* __restrict__ W1b,
                                                   float* __restrict__ part2) {
    __shared__ __align__(16) float sA[64 * 21];
    const int t = threadIdx.x, cb = blockIdx.x, kc = blockIdx.y;
    const int k0 = kc * 64;
    for (int idx = t; idx < NN * 64; idx += 256) {
        const int i = idx / 64, c = idx % 64;
        const int k = k0 + c;
        float s = b1a[k];
#pragma unroll
        for (int cc = 0; cc < 16; ++cc) s += part1[((size_t)cc * NN + i) * HID + k];
        sA[c * 21 + i] = s > 0.f ? s : 0.f;
    }
    __syncthreads();
    gemm_inner<64, HID>(cb * 1024 + 4 * t, kc, W1b, part2, sA);
}

// K3: part3 = (M @ relu(reduce32(part2)+b1b)) @ W2a.  K=2048, BK=64; grid (4,32)
__global__ __launch_bounds__(256, 2) void gemm_l2a(const float* __restrict__ part2,
                                                   const float* __restrict__ b1b,
                                                   const int* __restrict__ ei,
                                                   const float* __restrict__ W2a,
                                                   float* __restrict__ part3) {
    __shared__ __align__(16) float sA[64 * 21];
    __shared__ __align__(16) float sZ[64 * 21];
    __shared__ float sM[NN * NN];
    __shared__ int scratch[NN * NN + 1];
    const int t = threadIdx.x, cb = blockIdx.x, kc = blockIdx.y;
    const int k0 = kc * 64;
    build_M(ei, sM, scratch, t, 256);
    for (int idx = t; idx < NN * 64; idx += 256) {
        const int i = idx / 64, c = idx % 64;
        const int k = k0 + c;
        float s = b1b[k];
#pragma unroll
        for (int cc = 0; cc < 32; ++cc) s += part2[((size_t)cc * NN + i) * HID + k];
        sZ[c * 21 + i] = s > 0.f ? s : 0.f;
    }
    __syncthreads();
    for (int idx = t; idx < NN * 64; idx += 256) {
        const int i = idx / 64, c = idx % 64;
        float acc = 0.f;
#pragma unroll
        for (int s = 0; s < NN; ++s) acc = fmaf(sM[i * NN + s], sZ[c * 21 + s], acc);
        sA[c * 21 + i] = acc;
    }
    __syncthreads();
    gemm_inner<64, NT>(cb * 1024 + 4 * t, kc, W2a, part3, sA);
}

// K4: part4 = relu(reduce32(part3)+b2a) @ W2b.  K=4096, BK=64; grid (4, 64)
__global__ __launch_bounds__(256, 2) void gemm_l2b(const float* __restrict__ part3,
                                                   const float* __restrict__ b2a,
                                                   const float* __restrict__ W2b,
                                                   float* __restrict__ part4) {
    __shared__ __align__(16) float sA[64 * 21];
    const int t = threadIdx.x, cb = blockIdx.x, kc = blockIdx.y;
    const int k0 = kc * 64;
    for (int idx = t; idx < NN * 64; idx += 256) {
        const int i = idx / 64, c = idx % 64;
        const int k = k0 + c;
        float s = b2a[k];
#pragma unroll
        for (int cc = 0; cc < 32; ++cc) s += part3[((size_t)cc * NN + i) * NT + k];
        sA[c * 21 + i] = s > 0.f ? s : 0.f;
    }
    __syncthreads();
    gemm_inner<64, NT>(cb * 1024 + 4 * t, kc, W2b, part4, sA);
}

// ---------------------------------------------------------------------------
// K5 (fused classifier, DMA-staged): 1024 blocks x 256 threads, 76 rows each.
//   phase 1: sF[0..76) = reduce64(part4)+b2b  -> out+1 and LDS
//   phase 2: 19 chunks of 4 rows; Wc1 slice DMA'd to LDS via global_load_lds
//            (4-buffer pipeline, counted vmcnt, 1 barrier/chunk);
//            thread owns 2 cols, accumulates sF[row]*Wc1[row][col].
//   phase 3: dot with Wc2, tree-reduce, scal[bid]; ticket: last block sums.
// ---------------------------------------------------------------------------
__global__ __launch_bounds__(256, 4) void cls_fused(const float* __restrict__ part4,
                                                    const float* __restrict__ b2b,
                                                    const float* __restrict__ Wc1,
                                                    const float* __restrict__ bc1,
                                                    const float* __restrict__ Wc2,
                                                    const float* __restrict__ bc2,
                                                    float* __restrict__ out,
                                                    float* __restrict__ scal,
                                                    unsigned int* __restrict__ counter) {
    __shared__ __align__(16) float sW[4 * 2048];  // 4 bufs x (4 rows x 512)
    __shared__ float sF[76];
    __shared__ float red[256];
    __shared__ int lastFlag;
    const int t = threadIdx.x;
    const int lane = t & 63, wid = t >> 6;
    const int bid = blockIdx.x;
    const int k0 = bid * 76;

    // ---- issue first two DMA chunks before phase 1 (overlap) ----
    const float* __restrict__ wbase = Wc1 + (size_t)k0 * 512;
    {
        const float* g0 = wbase + wid * 512 + lane * 4;
        float* l0 = sW + wid * 512;
        stage16B(g0, l0);
        stage16B(g0 + 256, l0 + 256);
        const float* g1 = wbase + 2048 + wid * 512 + lane * 4;
        float* l1 = sW + 2048 + wid * 512;
        stage16B(g1, l1);
        stage16B(g1 + 256, l1 + 256);
    }

    // ---- phase 1: flat segment = reduce64(part4)+b2b ----
    const int e = t & 127, h = t >> 7;
    float partial = 0.f;
    if (e < 76) {
        const int fidx = k0 + e;
        const int i = fidx >> 12, n = fidx & 4095;
        const float* __restrict__ p = part4 + ((size_t)(h * 32 * NN + i)) * NT + n;
#pragma unroll 16
        for (int cc = 0; cc < 32; ++cc) partial += p[(size_t)cc * NN * NT];
    }
    if (e < 76 && h) red[e] = partial;
    __syncthreads();
    if (e < 76 && !h) {
        const int fidx = k0 + e;
        const float s = partial + red[e] + b2b[fidx & 4095];
        sF[e] = s;
        out[1 + fidx] = s;
    }

    // ---- phase 2: 19 chunks, 4-buffer DMA pipeline ----
    float accx = 0.f, accy = 0.f;
#pragma unroll 1
    for (int c = 0; c < 19; ++c) {
        if (c + 2 < 19) {
            const float* g = wbase + (size_t)(c + 2) * 2048 + wid * 512 + lane * 4;
            float* l = sW + ((c + 2) & 3) * 2048 + wid * 512;
            stage16B(g, l);
            stage16B(g + 256, l + 256);
            asm volatile("s_waitcnt vmcnt(4)" ::: "memory");
        } else if (c + 1 < 19) {
            asm volatile("s_waitcnt vmcnt(2)" ::: "memory");
        } else {
            asm volatile("s_waitcnt vmcnt(0)" ::: "memory");
        }
        __syncthreads();
        const float* wb = sW + (c & 3) * 2048;
#pragma unroll
        for (int r = 0; r < 4; ++r) {
            const float2 wv = *(const float2*)(wb + r * 512 + 2 * t);
            const float f = sF[c * 4 + r];
            accx = fmaf(f, wv.x, accx);
            accy = fmaf(f, wv.y, accy);
        }
    }

    // ---- phase 3: dot with Wc2, block scalar, ticket tail ----
    const float2 wv2 = ((const float2*)Wc2)[t];
    __syncthreads();
    red[t] = accx * wv2.x + accy * wv2.y;
    __syncthreads();
    for (int off = 128; off > 0; off >>= 1) {
        if (t < off) red[t] += red[t + off];
        __syncthreads();
    }
    if (t == 0) scal[bid] = red[0];
    __threadfence();
    __syncthreads();
    if (t == 0) lastFlag = (atomicAdd(counter, 1u) == 1023u) ? 1 : 0;
    __syncthreads();
    if (!lastFlag) return;
    __threadfence();

    float s = 0.f;
#pragma unroll
    for (int c = 0; c < 4; ++c) s += scal[t + 256 * c];
    const float2 b1 = ((const float2*)bc1)[t];
    s += b1.x * wv2.x + b1.y * wv2.y;
    red[t] = s;
    __syncthreads();
    for (int off = 128; off > 0; off >>= 1) {
        if (t < off) red[t] += red[t + off];
        __syncthreads();
    }
    if (t == 0) out[0] = 1.f / (1.f + expf(-(red[0] + bc2[0])));
}

extern "C" void kernel_launch(void* const* d_in, const int* in_sizes, int n_in,
                              void* d_out, int out_size, void* d_ws, size_t ws_size,
                              hipStream_t stream) {
    const float* z   = (const float*)d_in[0];
    const int*   ei  = (const int*)d_in[1];
    const float* W1a = (const float*)d_in[2];
    const float* b1a = (const float*)d_in[3];
    const float* W1b = (const float*)d_in[4];
    const float* b1b = (const float*)d_in[5];
    const float* W2a = (const float*)d_in[6];
    const float* b2a = (const float*)d_in[7];
    const float* W2b = (const float*)d_in[8];
    const float* b2b = (const float*)d_in[9];
    const float* Wc1 = (const float*)d_in[10];
    const float* bc1 = (const float*)d_in[11];
    const float* Wc2 = (const float*)d_in[12];
    const float* bc2 = (const float*)d_in[13];
    float* out = (float*)d_out;
    float* ws  = (float*)d_ws;

    // workspace layout (float offsets)
    unsigned int* counter = (unsigned int*)ws;  // ticket, reset by K1 each call
    float* part1 = ws + 262144;    // 16*19*2048 =   622,592
    float* part2 = ws + 1048576;   // 32*19*2048 = 1,245,184
    float* part3 = ws + 2359296;   // 32*19*4096 = 2,490,368
    float* part4 = ws + 4980736;   // 64*19*4096 = 4,980,736
    float* scal  = ws + 10485760;  // 1024

    gemm_l1a<<<dim3(2, 16), 256, 0, stream>>>(z, ei, W1a, part1, counter);
    gemm_l1b<<<dim3(2, 32), 256, 0, stream>>>(part1, b1a, W1b, part2);
    gemm_l2a<<<dim3(4, 32), 256, 0, stream>>>(part2, b1b, ei, W2a, part3);
    gemm_l2b<<<dim3(4, 64), 256, 0, stream>>>(part3, b2a, W2b, part4);
    cls_fused<<<1024, 256, 0, stream>>>(part4, b2b, Wc1, bc1, Wc2, bc2,
                                        out, scal, counter);
}

// Round 10
// 190.335 us; speedup vs baseline: 1.5672x; 1.1414x over previous
//
#include <hip/hip_runtime.h>

#define NN 19        // nodes
#define NT 4096
#define LAT 512
#define HID 2048
#define NE 342       // edges

// ---------------------------------------------------------------------------
// Build M = I + adjacency-count (19x19) into sM from edge_idx. cnt[] aliases
// scratch LDS. Edge buffer may be int64 (pairs of int32) or int32, detected
// via odd-word check (values in [0,19) => int64 high words all zero).
// ---------------------------------------------------------------------------
__device__ __forceinline__ void build_M(const int* __restrict__ ei, float* sM,
                                        int* scratch, int t, int bs) {
    int* cnt = scratch;
    int* flag = scratch + NN * NN;
    if (t == 0) *flag = 0;
    for (int i = t; i < NN * NN; i += bs) cnt[i] = 0;
    __syncthreads();
    int f = 0;
    for (int i = t; i < NE; i += bs) f |= ei[2 * i + 1];
    if (f) atomicOr(flag, 1);
    __syncthreads();
    const bool i64 = (*flag == 0);
    for (int i = t; i < NE; i += bs) {
        const int s = i64 ? ei[2 * i] : ei[i];
        const int d = i64 ? ei[2 * NE + 2 * i] : ei[NE + i];
        atomicAdd(&cnt[d * NN + s], 1);
    }
    __syncthreads();
    for (int i = t; i < NN * NN; i += bs)
        sM[i] = (float)cnt[i] + ((i / NN) == (i % NN) ? 1.f : 0.f);
    __syncthreads();
}

// ---------------------------------------------------------------------------
// GEMM inner: acc[19][4 cols] over a BK k-slice staged in sA[k*21+i].
// float4 weight loads, 8 in flight. Writes partial chunk kc.
// ---------------------------------------------------------------------------
template <int BK, int N>
__device__ __forceinline__ void gemm_inner(int col, int kc,
                                           const float* __restrict__ W,
                                           float* __restrict__ part,
                                           const float* __restrict__ sA) {
    const int k0 = kc * BK;
    const float4* __restrict__ w = (const float4*)(W + (size_t)k0 * N + col);
    float4 acc[NN];
#pragma unroll
    for (int i = 0; i < NN; ++i) acc[i] = make_float4(0.f, 0.f, 0.f, 0.f);
#pragma unroll 1
    for (int kk = 0; kk < BK; kk += 8) {
        float4 wb[8];
#pragma unroll
        for (int u = 0; u < 8; ++u) wb[u] = w[(size_t)(kk + u) * (N / 4)];
#pragma unroll
        for (int u = 0; u < 8; ++u) {
#pragma unroll
            for (int i = 0; i < NN; ++i) {
                const float av = sA[(kk + u) * 21 + i];
                acc[i].x = fmaf(av, wb[u].x, acc[i].x);
                acc[i].y = fmaf(av, wb[u].y, acc[i].y);
                acc[i].z = fmaf(av, wb[u].z, acc[i].z);
                acc[i].w = fmaf(av, wb[u].w, acc[i].w);
            }
        }
    }
    float* __restrict__ p = part + (size_t)kc * NN * N + col;
#pragma unroll
    for (int i = 0; i < NN; ++i) *(float4*)(p + (size_t)i * N) = acc[i];
}

// K1: part1 = (M @ z) @ W1a.  K=512, BK=32; grid (cb=2, kc=16). Zeroes ticket.
__global__ __launch_bounds__(256) void gemm_l1a(const float* __restrict__ z,
                                                const int* __restrict__ ei,
                                                const float* __restrict__ W1a,
                                                float* __restrict__ part1,
                                                unsigned int* __restrict__ counter) {
    __shared__ __align__(16) float sA[32 * 21];
    __shared__ __align__(16) float sZ[32 * 21];
    __shared__ float sM[NN * NN];
    __shared__ int scratch[NN * NN + 1];
    const int t = threadIdx.x, cb = blockIdx.x, kc = blockIdx.y;
    const int k0 = kc * 32;
    if (cb == 0 && kc == 0 && t == 0) *counter = 0u;
    build_M(ei, sM, scratch, t, 256);
    for (int idx = t; idx < NN * 32; idx += 256) {
        const int s = idx / 32, c = idx % 32;
        sZ[c * 21 + s] = z[(size_t)s * LAT + k0 + c];
    }
    __syncthreads();
    for (int idx = t; idx < NN * 32; idx += 256) {
        const int i = idx / 32, c = idx % 32;
        float acc = 0.f;
#pragma unroll
        for (int s = 0; s < NN; ++s) acc = fmaf(sM[i * NN + s], sZ[c * 21 + s], acc);
        sA[c * 21 + i] = acc;
    }
    __syncthreads();
    gemm_inner<32, HID>(cb * 1024 + 4 * t, kc, W1a, part1, sA);
}

// K2: part2 = relu(reduce16(part1)+b1a) @ W1b.  K=2048, BK=64; grid (2, 32)
__global__ __launch_bounds__(256) void gemm_l1b(const float* __restrict__ part1,
                                                const float* __restrict__ b1a,
                                                const float* __restrict__ W1b,
                                                float* __restrict__ part2) {
    __shared__ __align__(16) float sA[64 * 21];
    const int t = threadIdx.x, cb = blockIdx.x, kc = blockIdx.y;
    const int k0 = kc * 64;
    for (int idx = t; idx < NN * 64; idx += 256) {
        const int i = idx / 64, c = idx % 64;
        const int k = k0 + c;
        float s = b1a[k];
#pragma unroll
        for (int cc = 0; cc < 16; ++cc) s += part1[((size_t)cc * NN + i) * HID + k];
        sA[c * 21 + i] = s > 0.f ? s : 0.f;
    }
    __syncthreads();
    gemm_inner<64, HID>(cb * 1024 + 4 * t, kc, W1b, part2, sA);
}

// K3: part3 = (M @ relu(reduce32(part2)+b1b)) @ W2a.  K=2048, BK=64; grid (4,32)
__global__ __launch_bounds__(256) void gemm_l2a(const float* __restrict__ part2,
                                                const float* __restrict__ b1b,
                                                const int* __restrict__ ei,
                                                const float* __restrict__ W2a,
                                                float* __restrict__ part3) {
    __shared__ __align__(16) float sA[64 * 21];
    __shared__ __align__(16) float sZ[64 * 21];
    __shared__ float sM[NN * NN];
    __shared__ int scratch[NN * NN + 1];
    const int t = threadIdx.x, cb = blockIdx.x, kc = blockIdx.y;
    const int k0 = kc * 64;
    build_M(ei, sM, scratch, t, 256);
    for (int idx = t; idx < NN * 64; idx += 256) {
        const int i = idx / 64, c = idx % 64;
        const int k = k0 + c;
        float s = b1b[k];
#pragma unroll
        for (int cc = 0; cc < 32; ++cc) s += part2[((size_t)cc * NN + i) * HID + k];
        sZ[c * 21 + i] = s > 0.f ? s : 0.f;
    }
    __syncthreads();
    for (int idx = t; idx < NN * 64; idx += 256) {
        const int i = idx / 64, c = idx % 64;
        float acc = 0.f;
#pragma unroll
        for (int s = 0; s < NN; ++s) acc = fmaf(sM[i * NN + s], sZ[c * 21 + s], acc);
        sA[c * 21 + i] = acc;
    }
    __syncthreads();
    gemm_inner<64, NT>(cb * 1024 + 4 * t, kc, W2a, part3, sA);
}

// K4: part4 = relu(reduce32(part3)+b2a) @ W2b.  K=4096, BK=64; grid (4, 64)
__global__ __launch_bounds__(256) void gemm_l2b(const float* __restrict__ part3,
                                                const float* __restrict__ b2a,
                                                const float* __restrict__ W2b,
                                                float* __restrict__ part4) {
    __shared__ __align__(16) float sA[64 * 21];
    const int t = threadIdx.x, cb = blockIdx.x, kc = blockIdx.y;
    const int k0 = kc * 64;
    for (int idx = t; idx < NN * 64; idx += 256) {
        const int i = idx / 64, c = idx % 64;
        const int k = k0 + c;
        float s = b2a[k];
#pragma unroll
        for (int cc = 0; cc < 32; ++cc) s += part3[((size_t)cc * NN + i) * NT + k];
        sA[c * 21 + i] = s > 0.f ? s : 0.f;
    }
    __syncthreads();
    gemm_inner<64, NT>(cb * 1024 + 4 * t, kc, W2b, part4, sA);
}

// K5: flat = reduce64(part4)+b2b -> out+1.  76 blocks x 256 threads, float4.
__global__ __launch_bounds__(256) void reduce_out(const float* __restrict__ part4,
                                                  const float* __restrict__ b2b,
                                                  float* __restrict__ out1) {
    const int f = blockIdx.x * 256 + threadIdx.x;
    const int i = f / (NT / 4), n4 = f % (NT / 4);
    const float4 b = ((const float4*)b2b)[n4];
    float4 s = b;
    const float4* __restrict__ p = (const float4*)part4 + (size_t)i * (NT / 4) + n4;
#pragma unroll 16
    for (int c = 0; c < 64; ++c) {
        const float4 v = p[(size_t)c * NN * (NT / 4)];
        s.x += v.x; s.y += v.y; s.z += v.z; s.w += v.w;
    }
    float* __restrict__ o = out1 + ((size_t)i * (NT / 4) + n4) * 4;
    o[0] = s.x; o[1] = s.y; o[2] = s.z; o[3] = s.w;
}

// ---------------------------------------------------------------------------
// K6 (grid-stride classifier): 512 blocks x 256 threads.
//   Block b, step s reads row k = s*512 + b of Wc1 (device-wide DENSE 1 MB
//   window sweeping Wc1 sequentially -> HBM row-buffer locality).
//   Thread t owns cols (2t, 2t+1); flat[k] is wave-uniform (scalar load).
//   Per-block partial dotted with Wc2 -> scal[b]; ticket: last of 512 blocks
//   sums scalars + bc1.Wc2 + bc2 -> sigmoid -> out[0].
// ---------------------------------------------------------------------------
__global__ __launch_bounds__(256) void cls_gs(const float* __restrict__ flat,
                                              const float* __restrict__ Wc1,
                                              const float* __restrict__ bc1,
                                              const float* __restrict__ Wc2,
                                              const float* __restrict__ bc2,
                                              float* __restrict__ out,
                                              float* __restrict__ scal,
                                              unsigned int* __restrict__ counter) {
    __shared__ float red[256];
    __shared__ int lastFlag;
    const int t = threadIdx.x;
    const int b = blockIdx.x;  // 0..511
    const float2* __restrict__ wp = (const float2*)Wc1 + t;

    float accx = 0.f, accy = 0.f;
#pragma unroll 1
    for (int s = 0; s < 152; s += 8) {  // 77824 rows = 152 steps x 512 blocks
        float2 wb[8];
        float fv[8];
#pragma unroll
        for (int u = 0; u < 8; ++u)
            wb[u] = wp[(size_t)((s + u) * 512 + b) * 256];
#pragma unroll
        for (int u = 0; u < 8; ++u)
            fv[u] = flat[(s + u) * 512 + b];
#pragma unroll
        for (int u = 0; u < 8; ++u) {
            accx = fmaf(fv[u], wb[u].x, accx);
            accy = fmaf(fv[u], wb[u].y, accy);
        }
    }

    // block scalar = partial . Wc2
    const float2 wv2 = ((const float2*)Wc2)[t];
    red[t] = accx * wv2.x + accy * wv2.y;
    __syncthreads();
    for (int off = 128; off > 0; off >>= 1) {
        if (t < off) red[t] += red[t + off];
        __syncthreads();
    }
    if (t == 0) scal[b] = red[0];
    __threadfence();  // release scal device-wide (cross-XCD)
    __syncthreads();
    if (t == 0) lastFlag = (atomicAdd(counter, 1u) == 511u) ? 1 : 0;
    __syncthreads();
    if (!lastFlag) return;
    __threadfence();  // acquire before reading all scal

    float s = scal[t] + scal[t + 256];
    const float2 b1 = ((const float2*)bc1)[t];
    s += b1.x * wv2.x + b1.y * wv2.y;
    red[t] = s;
    __syncthreads();
    for (int off = 128; off > 0; off >>= 1) {
        if (t < off) red[t] += red[t + off];
        __syncthreads();
    }
    if (t == 0) out[0] = 1.f / (1.f + expf(-(red[0] + bc2[0])));
}

extern "C" void kernel_launch(void* const* d_in, const int* in_sizes, int n_in,
                              void* d_out, int out_size, void* d_ws, size_t ws_size,
                              hipStream_t stream) {
    const float* z   = (const float*)d_in[0];
    const int*   ei  = (const int*)d_in[1];
    const float* W1a = (const float*)d_in[2];
    const float* b1a = (const float*)d_in[3];
    const float* W1b = (const float*)d_in[4];
    const float* b1b = (const float*)d_in[5];
    const float* W2a = (const float*)d_in[6];
    const float* b2a = (const float*)d_in[7];
    const float* W2b = (const float*)d_in[8];
    const float* b2b = (const float*)d_in[9];
    const float* Wc1 = (const float*)d_in[10];
    const float* bc1 = (const float*)d_in[11];
    const float* Wc2 = (const float*)d_in[12];
    const float* bc2 = (const float*)d_in[13];
    float* out = (float*)d_out;
    float* ws  = (float*)d_ws;

    // workspace layout (float offsets)
    unsigned int* counter = (unsigned int*)ws;  // ticket, reset by K1 each call
    float* part1 = ws + 262144;    // 16*19*2048 =   622,592
    float* part2 = ws + 1048576;   // 32*19*2048 = 1,245,184
    float* part3 = ws + 2359296;   // 32*19*4096 = 2,490,368
    float* part4 = ws + 4980736;   // 64*19*4096 = 4,980,736
    float* scal  = ws + 10485760;  // 512

    gemm_l1a<<<dim3(2, 16), 256, 0, stream>>>(z, ei, W1a, part1, counter);
    gemm_l1b<<<dim3(2, 32), 256, 0, stream>>>(part1, b1a, W1b, part2);
    gemm_l2a<<<dim3(4, 32), 256, 0, stream>>>(part2, b1b, ei, W2a, part3);
    gemm_l2b<<<dim3(4, 64), 256, 0, stream>>>(part3, b2a, W2b, part4);
    reduce_out<<<76, 256, 0, stream>>>(part4, b2b, out + 1);
    cls_gs<<<512, 256, 0, stream>>>(out + 1, Wc1, bc1, Wc2, bc2,
                                    out, scal, counter);
}